// Round 5
// baseline (55.194 us; speedup 1.0000x reference)
//
#include <hip/hip_runtime.h>

typedef __attribute__((ext_vector_type(8))) short short8;
typedef __attribute__((ext_vector_type(4))) float f32x4;
typedef unsigned int u32;

#define N_IN  4096
#define N_OUT 4096
#define NBAT  256

#define OUT_ACT   0
#define OUT_FICT  1048576
#define OUT_PHYS  2097152
#define OUT_LUT   3145728
#define OUT_TLAST 3211264

// ws layout (~19 MB; ws is ~256 MB per harness fillBuffer)
#define WS_AIMG   0                       // 2 MB bf16 mask image, fragment layout
#define WS_PART   2097152                 // 16 MB fp32 partials [4][256][4096]
#define WS_DTF    (WS_PART + 16777216)
#define WS_DXA    (WS_DTF + 1024)

#define BM 128
#define BN 32
#define BK 64
#define SPLITK 4
#define KCHUNK (N_IN / SPLITK)            // 1024
#define NTK (KCHUNK / BK)                 // 16 K-tiles per block

__device__ __forceinline__ unsigned f2bf(float f) {
  unsigned u = __float_as_uint(f);
  return (u + 0x7FFFu + ((u >> 16) & 1u)) >> 16;   // RNE to bf16
}

// ---------------------------------------------------------------------------
// Kernel A: prepass. XOR-parity + delta_t + t_last, AND writes the mask as a
// bf16 image in MFMA-FRAGMENT layout:
//   byte_addr(b,k) = ((rg*64+ktg)*4 + kk*2+mi)*1024 + (l4*16+l15)*16 + j*2
//   rg=b>>5, mi=(b>>4)&1, l15=b&15, ktg=k>>6, kk=(k>>5)&1, l4=(k>>3)&3, j=k&7
// so the GEMM loads A-fragments register-direct, 1KB coalesced per instr.
// ---------------------------------------------------------------------------
__global__ __launch_bounds__(256) void snn_pre(
    const int* __restrict__ mask, const int* __restrict__ t_ptr,
    const int* __restrict__ pid, const int* __restrict__ t_last,
    float* __restrict__ dtf_ws, int* __restrict__ dxa_ws,
    char* __restrict__ aimg, float* __restrict__ out)
{
  const int b = blockIdx.x, tid = threadIdx.x;
  const int k0 = tid * 16;
  const int4* mp = (const int4*)(mask + (size_t)b * N_IN + k0);
  const int4* pp = (const int4*)(pid + k0);
  int x = 0;
  u32 wv[8];
#pragma unroll
  for (int q = 0; q < 4; ++q) {
    int4 m = mp[q];
    int4 id = pp[q];
    x ^= (m.x ? id.x : 0) ^ (m.y ? id.y : 0) ^ (m.z ? id.z : 0) ^ (m.w ? id.w : 0);
    wv[q * 2]     = (m.x ? 0x3F80u : 0u) | ((m.y ? 0x3F80u : 0u) << 16);
    wv[q * 2 + 1] = (m.z ? 0x3F80u : 0u) | ((m.w ? 0x3F80u : 0u) << 16);
  }
  {
    const int rg = b >> 5, rl = b & 31;
    const int mi = rl >> 4, l15 = rl & 15;
    const int ktg = tid >> 2, kk = (tid >> 1) & 1, l4_0 = (tid & 1) * 2;
    char* base = aimg + ((size_t)((rg * 64 + ktg) * 4 + kk * 2 + mi) << 10);
    uint4 v0; v0.x = wv[0]; v0.y = wv[1]; v0.z = wv[2]; v0.w = wv[3];
    uint4 v1; v1.x = wv[4]; v1.y = wv[5]; v1.z = wv[6]; v1.w = wv[7];
    *(uint4*)(base + (l4_0 * 16 + l15) * 16)       = v0;
    *(uint4*)(base + ((l4_0 + 1) * 16 + l15) * 16) = v1;
  }
  x ^= __shfl_xor(x, 32); x ^= __shfl_xor(x, 16); x ^= __shfl_xor(x, 8);
  x ^= __shfl_xor(x, 4);  x ^= __shfl_xor(x, 2);  x ^= __shfl_xor(x, 1);
  __shared__ int wx[4];
  if ((tid & 63) == 0) wx[tid >> 6] = x;
  __syncthreads();
  if (tid == 0) {
    int acc = wx[0] ^ wx[1] ^ wx[2] ^ wx[3];
    int tt = t_ptr[0];
    int dt = (tt - t_last[b]) & 15;
    dtf_ws[b] = (float)dt;
    dxa_ws[b] = dt ^ (acc & 15);
    out[OUT_TLAST + b] = (float)tt;
  }
}

// ---------------------------------------------------------------------------
// Kernel B: bf16 MFMA GEMM, split-K=4. Barrier-never-waits-on-global design:
//   A: register-direct fragment loads from aimg (no LDS, no barrier), depth-2.
//   B: fp32 dwordx4 loads depth-2 -> in-register transpose to bf16 -> LDS
//      (XOR-swizzled [n][k]); per tile ONE lgkmcnt(0)+s_barrier (LDS-only wait).
//   Compiler's counted vmcnt covers global loads issued 2 phases (~2P) ahead.
// ---------------------------------------------------------------------------
__global__ __launch_bounds__(256) void snn_gemm(
    const char* __restrict__ aimg, const float* __restrict__ synw,
    float* __restrict__ part)
{
  __shared__ __align__(16) char ldsB[2][BN * BK * 2];   // 2 x 4 KB

  const int tid = threadIdx.x;
  const int lane = tid & 63, wid = tid >> 6;
  const int l15 = lane & 15, l4 = lane >> 4;

  // bijective XCD swizzle (1024 blocks, 8 XCDs): 8 consecutive sids share nb
  const int bid = blockIdx.x;
  const int sid = (bid & 7) * 128 + (bid >> 3);
  const int nb = sid >> 3;          // 0..127  B panel shared within XCD chunk
  const int mb = (sid >> 2) & 1;    // 0..1
  const int kc = sid & 3;           // 0..3
  const int bmb = mb * BM, bnb = nb * BN, kcb = kc * KCHUNK;
  const int rg = mb * 4 + wid;

  // A fragment base: tile t adds t*4096, frag f adds f*1024
  const char* a_base = aimg + (((size_t)(rg * 64 + kc * 16) * 4) << 10) + lane * 16;

  // B slots: thread covers rows (b_rr, b_rr+1), cols b_n0..b_n0+3
  const int b_rr = (tid & 31) * 2;
  const int b_n0 = (tid >> 5) * 4;
  const float* b_base = synw + ((size_t)(kcb + b_rr) << 12) + bnb + b_n0;

  auto loadA = [&](int t, uint4* d) {
    const char* p = a_base + ((size_t)t << 12);
#pragma unroll
    for (int f = 0; f < 4; ++f) d[f] = *(const uint4*)(p + (f << 10));
  };
  auto loadB = [&](int t, float4* d) {
    const float* p = b_base + ((size_t)t << 18);   // t*64*4096 floats
    d[0] = *(const float4*)(p);
    d[1] = *(const float4*)(p + 4096);
  };
  auto writeB = [&](const float4* v, int buf) {
    const float* r0 = (const float*)&v[0];
    const float* r1 = (const float*)&v[1];
#pragma unroll
    for (int i = 0; i < 4; ++i) {
      int n = b_n0 + i;
      u32 pk = f2bf(r0[i]) | (f2bf(r1[i]) << 16);   // (k, k+1) bf16 pair
      *(u32*)(&ldsB[buf][n * 128 + (((b_rr >> 3) ^ (n & 7)) << 4) + ((b_rr & 7) << 1)]) = pk;
    }
  };

  f32x4 acc[2][2] = {};

  auto compute = [&](int buf, const uint4* af) {
#pragma unroll
    for (int kk = 0; kk < 2; ++kk) {
      const int g0 = kk * 4 + l4;
      short8 a[2], b[2];
#pragma unroll
      for (int mi = 0; mi < 2; ++mi)
        a[mi] = *(const short8*)&af[kk * 2 + mi];
#pragma unroll
      for (int nj = 0; nj < 2; ++nj) {
        int col = nj * 16 + l15;
        b[nj] = *(const short8*)(&ldsB[buf][col * 128 + ((g0 ^ (col & 7)) << 4)]);
      }
#pragma unroll
      for (int mi = 0; mi < 2; ++mi)
#pragma unroll
        for (int nj = 0; nj < 2; ++nj)
          acc[mi][nj] = __builtin_amdgcn_mfma_f32_16x16x32_bf16(a[mi], b[nj], acc[mi][nj], 0, 0, 0);
    }
  };

  uint4  aA[4], aB[4];
  float4 bA[2], bB[2];

  // prologue: 2 tiles of A+B in flight
  loadB(0, bA); loadA(0, aA);
  loadB(1, bB); loadA(1, aB);

  // Per phase: writeB(t) [vmcnt auto-counted on 2-phase-old regs];
  // issue B(t+2); lgkmcnt(0)+barrier (LDS writes only); compute(t);
  // issue A(t+2) after MFMA consumed the old frags (WAR-safe in issue order).
#define PHASE(T, BV, AV, BUF)                                 \
  {                                                           \
    writeB(BV, BUF);                                          \
    if ((T) + 2 < NTK) loadB((T) + 2, BV);                    \
    asm volatile("s_waitcnt lgkmcnt(0)" ::: "memory");        \
    __builtin_amdgcn_s_barrier();                             \
    __builtin_amdgcn_sched_barrier(0);                        \
    compute(BUF, AV);                                         \
    if ((T) + 2 < NTK) loadA((T) + 2, AV);                    \
  }

  for (int t = 0; t < NTK; t += 2) {
    PHASE(t,     bA, aA, 0)
    PHASE(t + 1, bB, aB, 1)
  }
#undef PHASE

  float* pb = part + (size_t)kc * (NBAT * N_OUT);
#pragma unroll
  for (int mi = 0; mi < 2; ++mi)
#pragma unroll
    for (int nj = 0; nj < 2; ++nj) {
      const int o = bnb + nj * 16 + l15;
#pragma unroll
      for (int r = 0; r < 4; ++r) {
        const int b = bmb + wid * 32 + mi * 16 + l4 * 4 + r;
        pb[(size_t)b * N_OUT + o] = acc[mi][nj][r];
      }
    }
}

// ---------------------------------------------------------------------------
// Kernel C: split-K reduce + fused epilogue (decay, phys, act).
// ---------------------------------------------------------------------------
__global__ __launch_bounds__(256) void snn_reduce(
    const float* __restrict__ part, const float* __restrict__ memf,
    const int* __restrict__ memp, const float* __restrict__ tau,
    const float* __restrict__ vth, const float* __restrict__ mem_map,
    const float* __restrict__ dtf_ws, const int* __restrict__ dxa_ws,
    float* __restrict__ out)
{
  const int flat = (blockIdx.x * 256 + threadIdx.x) * 4;
  const int b = flat >> 12, o = flat & 4095;
  const float4 p0 = *(const float4*)(part + flat);
  const float4 p1 = *(const float4*)(part + 1048576 + flat);
  const float4 p2 = *(const float4*)(part + 2097152 + flat);
  const float4 p3 = *(const float4*)(part + 3145728 + flat);
  float4 ws;
  ws.x = (p0.x + p1.x) + (p2.x + p3.x);
  ws.y = (p0.y + p1.y) + (p2.y + p3.y);
  ws.z = (p0.z + p1.z) + (p2.z + p3.z);
  ws.w = (p0.w + p1.w) + (p2.w + p3.w);
  const float dtf = dtf_ws[b];
  const int dxa = dxa_ws[b];
  const float4 mf = *(const float4*)(memf + flat);
  const int4  mp = *(const int4*)(memp + flat);
  const float4 tv = *(const float4*)(tau + o);
  const float4 vv = *(const float4*)(vth + o);
  float4 act, fict, phys;
#define DO(c, oi) { float d = __expf(-tv.c * dtf); fict.c = mf.c * d + ws.c; \
                    int mpn = (mp.c ^ dxa) & 15; phys.c = (float)mpn; \
                    act.c = (mem_map[(o + oi) * 16 + mpn] >= vv.c) ? 1.f : 0.f; }
  DO(x, 0) DO(y, 1) DO(z, 2) DO(w, 3)
#undef DO
  *(float4*)(out + OUT_ACT  + flat) = act;
  *(float4*)(out + OUT_FICT + flat) = fict;
  *(float4*)(out + OUT_PHYS + flat) = phys;
}

// ---------------------------------------------------------------------------
// Kernel D: LUT scatter-add collapsed to per-(o,m) histogram.
// ---------------------------------------------------------------------------
__global__ __launch_bounds__(256) void snn_lut(
    const int* __restrict__ memp, const int* __restrict__ dxa_ws,
    const float* __restrict__ mem_map, const float* __restrict__ lut_in,
    float* __restrict__ out)
{
  __shared__ int mp[NBAT * 16];
  __shared__ int dxs[NBAT];
  const int tid = threadIdx.x;
  const int o0 = blockIdx.x * 16;
#pragma unroll
  for (int i = 0; i < 16; ++i) {
    int b = i * 16 + (tid >> 4);
    int oj = tid & 15;
    mp[b * 16 + oj] = memp[(size_t)b * N_OUT + o0 + oj];
  }
  dxs[tid] = dxa_ws[tid];
  __syncthreads();
  const int o_l = tid >> 4, m = tid & 15;
  int cnt = 0;
#pragma unroll 8
  for (int b = 0; b < NBAT; ++b) {
    int v = (mp[b * 16 + o_l] ^ dxs[b]) & 15;
    cnt += (v == m);
  }
  const int o = o0 + o_l;
  const float vmap = mem_map[o * 16 + m];
  out[OUT_LUT + o * 16 + m] = lut_in[o * 16 + m] + 0.5f * ((float)m - vmap) * (float)cnt;
}

// ---------------------------------------------------------------------------
extern "C" void kernel_launch(void* const* d_in, const int* in_sizes, int n_in,
                              void* d_out, int out_size, void* d_ws, size_t ws_size,
                              hipStream_t stream)
{
  const int*   mask    = (const int*)d_in[0];
  const int*   t_ptr   = (const int*)d_in[1];
  const int*   pid     = (const int*)d_in[2];
  const int*   t_last  = (const int*)d_in[3];
  const float* memf    = (const float*)d_in[4];
  const int*   memp    = (const int*)d_in[5];
  const float* lut_in  = (const float*)d_in[6];
  const float* tau     = (const float*)d_in[7];
  const float* vth     = (const float*)d_in[8];
  const float* synw    = (const float*)d_in[9];
  const float* mem_map = (const float*)d_in[10];
  float* out = (float*)d_out;

  char* wsb = (char*)d_ws;
  char*  aimg   = wsb + WS_AIMG;
  float* part   = (float*)(wsb + WS_PART);
  float* dtf_ws = (float*)(wsb + WS_DTF);
  int*   dxa_ws = (int*)(wsb + WS_DXA);

  snn_pre<<<NBAT, 256, 0, stream>>>(mask, t_ptr, pid, t_last, dtf_ws, dxa_ws, aimg, out);
  snn_gemm<<<(NBAT / BM) * (N_OUT / BN) * SPLITK, 256, 0, stream>>>(
      aimg, synw, part);
  snn_reduce<<<(NBAT * N_OUT) / 1024, 256, 0, stream>>>(
      part, memf, memp, tau, vth, mem_map, dtf_ws, dxa_ws, out);
  snn_lut<<<NBAT, 256, 0, stream>>>(memp, dxa_ws, mem_map, lut_in, out);
}